// Round 10
// baseline (6038.456 us; speedup 1.0000x reference)
//
#include <hip/hip_runtime.h>
#include <cstddef>

#define MDIM 512
#define DDIM 1024
#define BDIM 4096
#define NLAYERS 16

typedef float f32x2 __attribute__((ext_vector_type(2)));

__device__ __forceinline__ float softf(float v, float t) {
  // relu(v-t) - relu(-v-t) == copysign(max(|v|-t,0), v)
  return copysignf(fmaxf(fabsf(v) - t, 0.0f), v);
}

// ---------------------------------------------------------------------------
// C = P(rows x K, row-major) @ B(K x 4096, row-major), fused epilogue.
// Bit-exact accumulation: per output element one fma chain, k ascending
// (2-k chunks ascending, j ascending within chunk) — same per-element chain
// as rounds 1/5/8/9 (absmax 0.2304688). Packed v_pk_fma_f32 = two
// independent IEEE fmas, so pairing cols does not change any chain.
// Structure: NO LDS, NO barriers. Wave = 16 rows x 128 cols; lane -> 2 cols.
//  - A: wave-uniform loads (broadcast; ~1 L1 access, SGPR-addressed)
//  - B: per-lane float2 from global, 16-row reuse = 0.25 B/fma (L1 2x slack)
//  - register double-buffered 2-k chunks, static names (no dynamic indexing)
// MODE 0: layer-0 A-kernel; MODE 1: scan A-kernel; MODE 2: B-kernel (soft-Z)
// ---------------------------------------------------------------------------
template <int MODE, int K>
__global__ __launch_bounds__(256, 2) void gemm_pk(
    const float* __restrict__ P, const float* __restrict__ Bm,
    const float* __restrict__ xg, const float* __restrict__ Ep,
    const float* __restrict__ Lp, const float* __restrict__ Zp,
    const float* __restrict__ beta1, const float* __restrict__ beta2,
    const float* __restrict__ beta3, const float* __restrict__ ss2,
    const float* __restrict__ apar, const float* __restrict__ apar1, int k,
    float* __restrict__ O0, float* __restrict__ O1, float* __restrict__ O2) {
  const int tid = threadIdx.x;
  const int lane = tid & 63;
  const int w = __builtin_amdgcn_readfirstlane((int)(tid >> 6));
  const int m0 = blockIdx.x * 64 + w * 16;  // wave's 16 rows (uniform)
  const int c0 = blockIdx.y * 128 + lane * 2;  // thread's 2 cols

  const float* pA = P + (size_t)m0 * K;  // wave-uniform base
  const float* pB = Bm + c0;

  f32x2 acc[16];
#pragma unroll
  for (int r = 0; r < 16; ++r) acc[r] = (f32x2)(0.0f);

  f32x2 A0[16], A1[16], B0[2], B1[2];

  auto loadA = [&](f32x2(&Ab)[16], int k0) {
#pragma unroll
    for (int r = 0; r < 16; ++r)
      Ab[r] = *reinterpret_cast<const f32x2*>(pA + (size_t)r * K + k0);
  };
  auto loadB = [&](f32x2(&Bb)[2], int k0) {
#pragma unroll
    for (int j = 0; j < 2; ++j)
      Bb[j] = *reinterpret_cast<const f32x2*>(pB + (size_t)(k0 + j) * BDIM);
  };
  auto comp = [&](const f32x2(&Ab)[16], const f32x2(&Bb)[2]) {
#pragma unroll
    for (int j = 0; j < 2; ++j)
#pragma unroll
      for (int r = 0; r < 16; ++r) {
        const f32x2 av = {Ab[r][j], Ab[r][j]};
        acc[r] = __builtin_elementwise_fma(av, Bb[j], acc[r]);
      }
  };

  constexpr int NCH = K / 2;  // 512 or 256, even
  loadA(A0, 0);
  loadB(B0, 0);
#pragma unroll 1
  for (int t = 0; t + 2 <= NCH; t += 2) {
    loadA(A1, (t + 1) * 2);
    loadB(B1, (t + 1) * 2);
    comp(A0, B0);
    if (t + 2 < NCH) {
      loadA(A0, (t + 2) * 2);
      loadB(B0, (t + 2) * 2);
    }
    comp(A1, B1);
  }

  // ---- epilogue (expressions identical to rounds 1/5/8/9) ----
  const float b1v = (MODE == 2) ? 0.f : beta1[k];
  float b2v = 0.f, b3v = 0.f, s2v = 0.f, a1v = 0.f, ap = 0.f;
  if (MODE == 1) {
    b2v = beta2[k - 1];
    b3v = beta3[k - 1];
    s2v = ss2[k - 1];
    a1v = apar1[k - 1];
  }
  if (MODE == 2) ap = apar[k];

#pragma unroll
  for (int r = 0; r < 16; ++r) {
    const size_t off = (size_t)(m0 + r) * BDIM + c0;
    if (MODE == 2) {
      const float2 z2 = *reinterpret_cast<const float2*>(&Zp[off]);
      float2 o;
      o.x = softf(z2.x - acc[r][0], ap);
      o.y = softf(z2.y - acc[r][1], ap);
      *reinterpret_cast<float2*>(&O0[off]) = o;
    } else {
      const float2 e2 = *reinterpret_cast<const float2*>(&Ep[off]);
      const float2 l2 = *reinterpret_cast<const float2*>(&Lp[off]);
      const float2 x2 = *reinterpret_cast<const float2*>(&xg[off]);
      const float ev[2] = {e2.x, e2.y};
      const float lv[2] = {l2.x, l2.y};
      const float xv[2] = {x2.x, x2.y};
      float vo[2], eo[2], lo_[2];
#pragma unroll
      for (int j = 0; j < 2; ++j) {
        const float az = acc[r][j];
        if (MODE == 0) {
          const float t0 = az + ev[j] - xv[j];
          vo[j] = fmaf(b1v, t0, lv[j]);
          eo[j] = ev[j];
          lo_[j] = lv[j];
        } else {
          const float vv = fmaf(b2v, az + ev[j] - xv[j], lv[j]);
          const float en = softf(ev[j] - s2v * vv, a1v);
          const float tn_ = az + en - xv[j];
          const float ln = fmaf(b3v, tn_, lv[j]);
          eo[j] = en;
          lo_[j] = ln;
          vo[j] = fmaf(b1v, tn_, ln);
        }
      }
      float2 t2;
      t2.x = vo[0];
      t2.y = vo[1];
      *reinterpret_cast<float2*>(&O0[off]) = t2;
      t2.x = eo[0];
      t2.y = eo[1];
      *reinterpret_cast<float2*>(&O1[off]) = t2;
      t2.x = lo_[0];
      t2.y = lo_[1];
      *reinterpret_cast<float2*>(&O2[off]) = t2;
    }
  }
}

extern "C" void kernel_launch(void* const* d_in, const int* in_sizes, int n_in,
                              void* d_out, int out_size, void* d_ws,
                              size_t ws_size, hipStream_t stream) {
  (void)in_sizes;
  (void)n_in;
  (void)out_size;
  (void)ws_size;
  const float* x = (const float*)d_in[0];
  const float* A = (const float*)d_in[1];
  const float* W = (const float*)d_in[2];
  const float* Z0 = (const float*)d_in[3];
  const float* E0 = (const float*)d_in[4];
  const float* L0 = (const float*)d_in[5];
  const float* beta1 = (const float*)d_in[6];
  const float* beta2 = (const float*)d_in[7];
  const float* beta3 = (const float*)d_in[8];
  const float* ss2 = (const float*)d_in[9];
  const float* apar = (const float*)d_in[10];
  const float* apar1 = (const float*)d_in[11];

  constexpr size_t DB = (size_t)DDIM * BDIM;
  constexpr size_t MB = (size_t)MDIM * BDIM;
  float* Zall = (float*)d_out;
  float* Eall = Zall + (size_t)NLAYERS * DB;
  float* Lall = Eall + (size_t)NLAYERS * MB;
  float* Var = (float*)d_ws;  // MDIM*BDIM floats = 8 MiB

  const dim3 blk(256);
  const dim3 gA(MDIM / 64, BDIM / 128);  // (8, 32)  = 256 blocks
  const dim3 gB(DDIM / 64, BDIM / 128);  // (16, 32) = 512 blocks

  // layer 0
  gemm_pk<0, DDIM><<<gA, blk, 0, stream>>>(
      A, Z0, x, E0, L0, nullptr, beta1, beta2, beta3, ss2, apar, apar1, 0, Var,
      Eall, Lall);
  gemm_pk<2, MDIM><<<gB, blk, 0, stream>>>(
      W, Var, nullptr, nullptr, nullptr, Z0, beta1, beta2, beta3, ss2, apar,
      apar1, 0, Zall, nullptr, nullptr);
  // layers 1..15
  for (int k = 1; k < NLAYERS; ++k) {
    const float* Zp = Zall + (size_t)(k - 1) * DB;
    gemm_pk<1, DDIM><<<gA, blk, 0, stream>>>(
        A, Zp, x, Eall + (size_t)(k - 1) * MB, Lall + (size_t)(k - 1) * MB,
        nullptr, beta1, beta2, beta3, ss2, apar, apar1, k, Var,
        Eall + (size_t)k * MB, Lall + (size_t)k * MB);
    gemm_pk<2, MDIM><<<gB, blk, 0, stream>>>(
        W + (size_t)k * DDIM * MDIM, Var, nullptr, nullptr, nullptr, Zp, beta1,
        beta2, beta3, ss2, apar, apar1, k, Zall + (size_t)k * DB, nullptr,
        nullptr);
  }
}

// Round 11
// 2282.456 us; speedup vs baseline: 2.6456x; 2.6456x over previous
//
#include <hip/hip_runtime.h>
#include <cstddef>

#define MDIM 512
#define DDIM 1024
#define BDIM 4096
#define NLAYERS 16

constexpr int BK = 16;

__device__ __forceinline__ float softf(float v, float t) {
  // relu(v-t) - relu(-v-t) == copysign(max(|v|-t,0), v)
  return copysignf(fmaxf(fabsf(v) - t, 0.0f), v);
}

// ---------------------------------------------------------------------------
// C = P(rows x K, row-major) @ B(K x 4096, row-major), fused epilogue.
// Bit-exact accumulation: per output element one fmaf chain, k ascending
// (BK=16 chunks ascending, kk ascending within chunk) — identical chain to
// rounds 1/5 (absmax 0.2304688).
// Register-tile maximization (B/fma is the binding resource):
//   TNW=4 (B-GEMM): BM=128, thread = 8 rows x {4 + 4} cols -> 1.0 B/fma
//   TNW=2 (A-GEMM): BM=64,  thread = 8 rows x {2 + 2} cols -> 1.5 B/fma
// BN=128 fixed; col groups at {g*64 + tn*TNW} keep LDS reads <=2-way (free).
// Double-buffered LDS, one barrier per chunk, gload issued before comp.
// MODE 0: layer-0 A-kernel; MODE 1: scan A-kernel; MODE 2: B-kernel (soft-Z)
// ---------------------------------------------------------------------------
template <int MODE, int K, int TNW>
__global__ __launch_bounds__(256) void gemm_rt(
    const float* __restrict__ P, const float* __restrict__ Bm,
    const float* __restrict__ xg, const float* __restrict__ Ep,
    const float* __restrict__ Lp, const float* __restrict__ Zp,
    const float* __restrict__ beta1, const float* __restrict__ beta2,
    const float* __restrict__ beta3, const float* __restrict__ ss2,
    const float* __restrict__ apar, const float* __restrict__ apar1, int k,
    float* __restrict__ O0, float* __restrict__ O1, float* __restrict__ O2) {
  constexpr int BM = 32 * TNW;        // 64 or 128
  constexpr int CT = 64 / TNW;        // col-threads: 32 or 16
  constexpr int APT = BM / 64;        // float4s of A staged per thread (1 or 2)
  __shared__ __align__(16) float As[2][BK][BM];
  __shared__ __align__(16) float Bs[2][BK][128];

  const int tid = threadIdx.x;
  const int tn = tid & (CT - 1);
  const int tm = tid / CT;            // 0..(BM/8-1)
  const int m0 = blockIdx.x * BM, n0 = blockIdx.y * 128;

  float acc[8][2][TNW];
#pragma unroll
  for (int r = 0; r < 8; ++r)
#pragma unroll
    for (int g = 0; g < 2; ++g)
#pragma unroll
      for (int j = 0; j < TNW; ++j) acc[r][g][j] = 0.0f;

  // A staging map
  const int ar = (APT == 1) ? (tid >> 2) : (tid >> 1);
  const int akc = (APT == 1) ? ((tid & 3) * 4) : ((tid & 1) * 8);
  const float* gA = P + (size_t)(m0 + ar) * K + akc;
  // B staging map: 4 rows x 2 float4 per thread covers 16x128
  const int br = tid >> 4, bc = (tid & 15) * 8;
  const float* gB = Bm + (size_t)br * BDIM + n0 + bc;

  float4 rA0, rA1, rB0, rB1;
  auto gload = [&](int k0) {
    rA0 = *reinterpret_cast<const float4*>(gA + (size_t)k0);
    if (APT == 2) rA1 = *reinterpret_cast<const float4*>(gA + (size_t)k0 + 4);
    rB0 = *reinterpret_cast<const float4*>(gB + (size_t)k0 * BDIM);
    rB1 = *reinterpret_cast<const float4*>(gB + (size_t)k0 * BDIM + 4);
  };
  auto stagewr = [&](int bb) {
    As[bb][akc + 0][ar] = rA0.x;
    As[bb][akc + 1][ar] = rA0.y;
    As[bb][akc + 2][ar] = rA0.z;
    As[bb][akc + 3][ar] = rA0.w;
    if (APT == 2) {
      As[bb][akc + 4][ar] = rA1.x;
      As[bb][akc + 5][ar] = rA1.y;
      As[bb][akc + 6][ar] = rA1.z;
      As[bb][akc + 7][ar] = rA1.w;
    }
    *reinterpret_cast<float4*>(&Bs[bb][br][bc]) = rB0;
    *reinterpret_cast<float4*>(&Bs[bb][br][bc + 4]) = rB1;
  };
  auto comp = [&](int bb) {
#pragma unroll
    for (int kk = 0; kk < BK; ++kk) {
      const float4 a0 = *reinterpret_cast<const float4*>(&As[bb][kk][tm * 8]);
      const float4 a1 =
          *reinterpret_cast<const float4*>(&As[bb][kk][tm * 8 + 4]);
      const float a[8] = {a0.x, a0.y, a0.z, a0.w, a1.x, a1.y, a1.z, a1.w};
      float bv[2][TNW];
#pragma unroll
      for (int g = 0; g < 2; ++g) {
        if (TNW == 4) {
          *reinterpret_cast<float4*>(&bv[g][0]) =
              *reinterpret_cast<const float4*>(&Bs[bb][kk][g * 64 + tn * 4]);
        } else {
          *reinterpret_cast<float2*>(&bv[g][0]) =
              *reinterpret_cast<const float2*>(&Bs[bb][kk][g * 64 + tn * 2]);
        }
      }
#pragma unroll
      for (int r = 0; r < 8; ++r)
#pragma unroll
        for (int g = 0; g < 2; ++g)
#pragma unroll
          for (int j = 0; j < TNW; ++j)
            acc[r][g][j] = fmaf(a[r], bv[g][j], acc[r][g][j]);
    }
  };

  constexpr int NS = K / BK;
  gload(0);
  stagewr(0);
  __syncthreads();
  int bb = 0;
#pragma unroll 1
  for (int t = 1; t < NS; ++t) {
    gload(t * BK);
    comp(bb);         // reads buffer bb
    stagewr(bb ^ 1);  // writes the other buffer — one barrier suffices
    __syncthreads();
    bb ^= 1;
  }
  comp(bb);

  // ---- epilogue (expressions identical to rounds 1/5) ----
  const float b1v = (MODE == 2) ? 0.f : beta1[k];
  float b2v = 0.f, b3v = 0.f, s2v = 0.f, a1v = 0.f, ap = 0.f;
  if (MODE == 1) {
    b2v = beta2[k - 1];
    b3v = beta3[k - 1];
    s2v = ss2[k - 1];
    a1v = apar1[k - 1];
  }
  if (MODE == 2) ap = apar[k];

#pragma unroll
  for (int r = 0; r < 8; ++r) {
    const int row = m0 + tm * 8 + r;
#pragma unroll
    for (int g = 0; g < 2; ++g) {
      const int col = n0 + g * 64 + tn * TNW;
      const size_t off = (size_t)row * BDIM + col;
      if (MODE == 2) {
        float z[TNW], o[TNW];
#pragma unroll
        for (int j = 0; j < TNW; ++j) z[j] = Zp[off + j];
#pragma unroll
        for (int j = 0; j < TNW; ++j) o[j] = softf(z[j] - acc[r][g][j], ap);
#pragma unroll
        for (int j = 0; j < TNW; ++j) O0[off + j] = o[j];
      } else {
        float ev[TNW], lv[TNW], xv[TNW];
#pragma unroll
        for (int j = 0; j < TNW; ++j) {
          ev[j] = Ep[off + j];
          lv[j] = Lp[off + j];
          xv[j] = xg[off + j];
        }
        float vo[TNW], eo[TNW], lo_[TNW];
#pragma unroll
        for (int j = 0; j < TNW; ++j) {
          const float az = acc[r][g][j];
          if (MODE == 0) {
            const float t0 = az + ev[j] - xv[j];
            vo[j] = fmaf(b1v, t0, lv[j]);
            eo[j] = ev[j];
            lo_[j] = lv[j];
          } else {
            const float vv = fmaf(b2v, az + ev[j] - xv[j], lv[j]);
            const float en = softf(ev[j] - s2v * vv, a1v);
            const float tn_ = az + en - xv[j];
            const float ln = fmaf(b3v, tn_, lv[j]);
            eo[j] = en;
            lo_[j] = ln;
            vo[j] = fmaf(b1v, tn_, ln);
          }
        }
#pragma unroll
        for (int j = 0; j < TNW; ++j) {
          O0[off + j] = vo[j];
          O1[off + j] = eo[j];
          O2[off + j] = lo_[j];
        }
      }
    }
  }
}

extern "C" void kernel_launch(void* const* d_in, const int* in_sizes, int n_in,
                              void* d_out, int out_size, void* d_ws,
                              size_t ws_size, hipStream_t stream) {
  (void)in_sizes;
  (void)n_in;
  (void)out_size;
  (void)ws_size;
  const float* x = (const float*)d_in[0];
  const float* A = (const float*)d_in[1];
  const float* W = (const float*)d_in[2];
  const float* Z0 = (const float*)d_in[3];
  const float* E0 = (const float*)d_in[4];
  const float* L0 = (const float*)d_in[5];
  const float* beta1 = (const float*)d_in[6];
  const float* beta2 = (const float*)d_in[7];
  const float* beta3 = (const float*)d_in[8];
  const float* ss2 = (const float*)d_in[9];
  const float* apar = (const float*)d_in[10];
  const float* apar1 = (const float*)d_in[11];

  constexpr size_t DB = (size_t)DDIM * BDIM;
  constexpr size_t MB = (size_t)MDIM * BDIM;
  float* Zall = (float*)d_out;
  float* Eall = Zall + (size_t)NLAYERS * DB;
  float* Lall = Eall + (size_t)NLAYERS * MB;
  float* Var = (float*)d_ws;  // MDIM*BDIM floats = 8 MiB

  const dim3 blk(256);
  const dim3 gA(MDIM / 64, BDIM / 128);   // (8, 32)  = 256 blocks, 8x{2+2}
  const dim3 gB(DDIM / 128, BDIM / 128);  // (8, 32)  = 256 blocks, 8x{4+4}

  // layer 0
  gemm_rt<0, DDIM, 2><<<gA, blk, 0, stream>>>(
      A, Z0, x, E0, L0, nullptr, beta1, beta2, beta3, ss2, apar, apar1, 0, Var,
      Eall, Lall);
  gemm_rt<2, MDIM, 4><<<gB, blk, 0, stream>>>(
      W, Var, nullptr, nullptr, nullptr, Z0, beta1, beta2, beta3, ss2, apar,
      apar1, 0, Zall, nullptr, nullptr);
  // layers 1..15
  for (int k = 1; k < NLAYERS; ++k) {
    const float* Zp = Zall + (size_t)(k - 1) * DB;
    gemm_rt<1, DDIM, 2><<<gA, blk, 0, stream>>>(
        A, Zp, x, Eall + (size_t)(k - 1) * MB, Lall + (size_t)(k - 1) * MB,
        nullptr, beta1, beta2, beta3, ss2, apar, apar1, k, Var,
        Eall + (size_t)k * MB, Lall + (size_t)k * MB);
    gemm_rt<2, MDIM, 4><<<gB, blk, 0, stream>>>(
        W + (size_t)k * DDIM * MDIM, Var, nullptr, nullptr, nullptr, Zp, beta1,
        beta2, beta3, ss2, apar, apar1, k, Zall + (size_t)k * DB, nullptr,
        nullptr);
  }
}